// Round 11
// baseline (1456.557 us; speedup 1.0000x reference)
//
#include <hip/hip_runtime.h>
#include <stdint.h>

#define Vv 512
#define Ff 1024

typedef unsigned short u16;
typedef unsigned long long u64;
typedef __attribute__((ext_vector_type(8))) short s16x8;
typedef __attribute__((ext_vector_type(4))) float f32x4;

// workspace layout (bytes)
#define OFF_WH  (0ull)
#define OFF_WM  (2ull << 20)
#define OFF_WL  (4ull << 20)
#define OFF_A0  (6ull << 20)
#define OFF_A1  (9ull << 20)
#define OFF_FLG (12ull << 20)

// A buffer: 256 tiles (ig 16 x js 16), tile = 12288 B: [lv 3][o 8][r 32] 16B units;
// element (i=ig*32+r, j=js*64+o*8+e) at tile*12288 + lv*4096 + (o*32+r)*16 + e*2.

// Exact 3-way bf16 truncation split: v == h + m + l (bit-exact, 24 mantissa bits)
__device__ __forceinline__ void split3(float v, u16& h, u16& m, u16& l) {
    unsigned u = __float_as_uint(v);
    float fh = __uint_as_float(u & 0xFFFF0000u);
    h = (u16)(u >> 16);
    float r1 = v - fh;                         // exact
    unsigned u1 = __float_as_uint(r1);
    float fm = __uint_as_float(u1 & 0xFFFF0000u);
    m = (u16)(u1 >> 16);
    float r2 = r1 - fm;                        // exact
    l = (u16)(__float_as_uint(r2) >> 16);
}

__device__ __forceinline__ float bf2f(short v) {
    return __uint_as_float(((unsigned)(u16)v) << 16);
}

// W planes. Wh/Wm frag-major: unit = (((js*4+nq)*16+c)*2+kh)*64 + o*16 + col.
// Wl (per js-block 8192 units, LDS-linear): unit = js*8192 + (c*2+kh)*256 + o*64 + nq*16 + col.
__global__ void wsplit_kernel(const float* __restrict__ W, char* __restrict__ ws) {
    int idx = blockIdx.x * 256 + threadIdx.x;   // 0..131071 (j x k-octet)
    int j = idx >> 7, ko = idx & 127;
    const float* wr = W + (size_t)j * Ff + ko * 8;
    s16x8 vh, vm, vl;
#pragma unroll
    for (int e = 0; e < 8; ++e) {
        u16 h, m, l; split3(wr[e], h, m, l);
        vh[e] = (short)h; vm[e] = (short)m; vl[e] = (short)l;
    }
    int js = j >> 6, nq = (j >> 4) & 3, col = j & 15;
    int c = ko >> 3, kh = (ko >> 2) & 1, o = ko & 3;
    unsigned uhm = (unsigned)((((js * 4 + nq) * 16 + c) * 2 + kh) * 64 + o * 16 + col);
    unsigned ul  = (unsigned)(js * 8192 + (c * 2 + kh) * 256 + o * 64 + nq * 16 + col);
    *(s16x8*)(ws + OFF_WH + (size_t)uhm * 16) = vh;
    *(s16x8*)(ws + OFF_WM + (size_t)uhm * 16) = vm;
    *(s16x8*)(ws + OFF_WL + (size_t)ul * 16)  = vl;
}

// t=0 state into A0 tiles + zero the tile flags (64 B stride -> 16 KB region)
__global__ void init_kernel(const float* __restrict__ X, const float* __restrict__ b,
                            char* __restrict__ ws) {
    int idx = blockIdx.x * 256 + threadIdx.x;   // 0..65535 (i x j-octet)
    if (idx < 4096) ((unsigned*)(ws + OFF_FLG))[idx] = 0u;
    int i = idx >> 7, jo = idx & 127;
    s16x8 vh, vm, vl;
#pragma unroll
    for (int e = 0; e < 8; ++e) {
        int j = jo * 8 + e;
        float u = b[j];
        if (j < Vv && i != j) u = 0.5f * u + 0.5f * X[j];
        u = fmaxf(u, 0.f);
        u16 h, m, l; split3(u, h, m, l);
        vh[e] = (short)h; vm[e] = (short)m; vl[e] = (short)l;
    }
    int ig = i >> 5, r = i & 31, js = jo >> 3, o = jo & 7;
    size_t tb = (size_t)(ig * 16 + js) * 12288 + (size_t)(o * 32 + r) * 16;
    *(s16x8*)(ws + OFF_A0 + tb)        = vh;
    *(s16x8*)(ws + OFF_A0 + tb + 4096) = vm;
    *(s16x8*)(ws + OFF_A0 + tb + 8192) = vl;
}

#define GST(addr, val) \
    asm volatile("global_store_dwordx2 %0, %1, off sc0 sc1" \
                 :: "v"((void*)(addr)), "v"(val) : "memory")
#define MM(acc_, a_, b_) \
    asm("v_mfma_f32_16x16x32_bf16 %0, %1, %2, %0" : "+v"(acc_) : "v"(a_), "v"(b_))

// Persistent: 256 blocks x 512 thr; block = (ig, js). 8 waves: kh = w&1, nq = w>>1.
// Wh/Wm STREAMED per chunk from the shared frag-major arrays (L2-resident; 1-chunk
// named-reg double buffer inside the counted-vmcnt pipeline). Wl LDS-resident.
// A chunks: reg-staged coherent GLD -> LDS dbuf (2x12 KB), one s_barrier per chunk.
__global__ __launch_bounds__(512, 2)
void mega_kernel(const float* __restrict__ X, const float* __restrict__ b,
                 char* __restrict__ ws) {
    extern __shared__ char smem[];   // Wl 131072 | A slots 2x12288 (red overlays slots)
    const int tid = threadIdx.x, bid = blockIdx.x;
    const int ig = bid >> 4, js = bid & 15;
    const int lane = tid & 63, l15 = lane & 15, l4 = lane >> 4;
    const int w = tid >> 6, kh = w & 1, nq = w >> 1;

    unsigned* flg = (unsigned*)(ws + OFF_FLG);

    // one-time: Wl 64-col slice -> LDS (linear, async)
    {
        const char* src = ws + OFF_WL + (size_t)js * 131072;
#pragma unroll
        for (int q = 0; q < 16; ++q) {
            unsigned u = (unsigned)(q * 512 + tid) * 16u;
            __builtin_amdgcn_global_load_lds(
                (const __attribute__((address_space(1))) void*)(src + u),
                (__attribute__((address_space(3))) void*)(smem + u), 16, 0, 0);
        }
    }

    // per-thread W fragment base (frag-major; chunk c at +c*2048)
    const char* wfrag = ws + OFF_WH +
        (size_t)(((((js * 4 + nq) * 16) * 2 + kh) * 64) + l4 * 16 + l15) * 16;

    const int row = tid >> 4, c4 = (tid & 15) * 4;
    const int i_glob = ig * 32 + row;
    const float4 bbv = *(const float4*)(b + js * 64 + c4);
    float* red = (float*)(smem + 131072);

    // per-thread constant LDS offsets
    const unsigned abase = (unsigned)(((kh * 4 + l4) * 32 + l15) * 16);
    const unsigned a00 = abase,          a01 = abase + 256;             // lv0, mf0/1
    const unsigned a10 = abase + 4096,   a11 = abase + 4096 + 256;      // lv1
    const unsigned a20 = abase + 8192,   a21 = abase + 8192 + 256;      // lv2
    const unsigned bloff = (unsigned)(kh * 4096 + (l4 * 64 + nq * 16 + l15) * 16);

    __syncthreads();   // Wl in LDS (barrier drains vmcnt)

    s16x8 Af00, Af01, Af10, Af11, Af20, Af21, Bl;
    s16x8 Wha, Wma, Whb, Wmb;
    u64 ga0, ga1, ga2, gb0, gb1, gb2;

#define GLDW(H_, M_, cc) do {                                                          \
        const char* wp_ = wfrag + (size_t)((cc) * 2048);                               \
        asm volatile("global_load_dwordx4 %0, %1, off"                                 \
                     : "=v"(H_) : "v"((const void*)wp_));                              \
        asm volatile("global_load_dwordx4 %0, %1, off"                                 \
                     : "=v"(M_) : "v"((const void*)(wp_ + (2ull << 20))));             \
    } while (0)
#define GLDA3(g0_, g1_, g2_, cc) do {                                                  \
        const char* ap_ = tb + (size_t)((cc) * 12288) + (size_t)tid * 8;               \
        asm volatile("global_load_dwordx2 %0, %1, off sc0 sc1"                         \
                     : "=v"(g0_) : "v"((const void*)ap_) : "memory");                  \
        asm volatile("global_load_dwordx2 %0, %1, off sc0 sc1"                         \
                     : "=v"(g1_) : "v"((const void*)(ap_ + 4096)) : "memory");         \
        asm volatile("global_load_dwordx2 %0, %1, off sc0 sc1"                         \
                     : "=v"(g2_) : "v"((const void*)(ap_ + 8192)) : "memory");         \
    } while (0)
#define DSWR3(slot, g0_, g1_, g2_) do {                                                \
        char* wp_ = smem + 131072 + (slot) * 12288 + (size_t)tid * 8;                  \
        *(u64*)(wp_) = g0_; *(u64*)(wp_ + 4096) = g1_; *(u64*)(wp_ + 8192) = g2_;      \
    } while (0)
#define DSRD7(slot, cc) do {                                                           \
        const char* sb_ = smem + 131072 + (slot) * 12288;                              \
        Af00 = *(const s16x8*)(sb_ + a00); Af01 = *(const s16x8*)(sb_ + a01);          \
        Af10 = *(const s16x8*)(sb_ + a10); Af11 = *(const s16x8*)(sb_ + a11);          \
        Af20 = *(const s16x8*)(sb_ + a20); Af21 = *(const s16x8*)(sb_ + a21);          \
        Bl = *(const s16x8*)(smem + (cc) * 8192 + bloff);                              \
    } while (0)
#define MFMA12W(H_, M_) do {                                                           \
        __builtin_amdgcn_s_setprio(1);                                                 \
        MM(acc0, Af00, H_); MM(acc1, Af01, H_);                                        \
        MM(acc0, Af00, M_); MM(acc1, Af01, M_);                                        \
        MM(acc0, Af10, H_); MM(acc1, Af11, H_);                                        \
        MM(acc0, Af00, Bl); MM(acc1, Af01, Bl);                                        \
        MM(acc0, Af20, H_); MM(acc1, Af21, H_);                                        \
        MM(acc0, Af10, M_); MM(acc1, Af11, M_);                                        \
        __builtin_amdgcn_s_setprio(0);                                                 \
    } while (0)
// middle chunk: load W(c+1) into (Hn,Mn), prefetch A(c+2) into P, compute c with
// (Hc,Mc), hand off A(c+1) from Q. Queue: A(c+1)x3, W(c+1)x2, A(c+2)x3 -> vmcnt(3).
#define CHUNK_MID(c, P0, P1, P2, Q0, Q1, Q2, Hc, Mc, Hn, Mn) do {                      \
        GLDW(Hn, Mn, (c) + 1);                                                         \
        GLDA3(P0, P1, P2, (c) + 2);                                                    \
        __builtin_amdgcn_sched_barrier(0);                                             \
        MFMA12W(Hc, Mc);                                                               \
        __builtin_amdgcn_sched_barrier(0);                                             \
        asm volatile("s_waitcnt vmcnt(3)" ::: "memory");                               \
        DSWR3(((c) + 1) & 1, Q0, Q1, Q2);                                              \
        asm volatile("s_waitcnt lgkmcnt(0)" ::: "memory");                             \
        __builtin_amdgcn_s_barrier();                                                  \
        DSRD7(((c) + 1) & 1, (c) + 1);                                                 \
    } while (0)

    for (int t = 1; t <= 126; ++t) {
        char* srcA = ws + ((t & 1) ? OFF_A0 : OFF_A1);
        char* dstA = ws + ((t & 1) ? OFF_A1 : OFF_A0);

        // wait all 16 producer tiles of row ig at step t-1 (parallel poll)
        if (tid < 16) {
            while ((int)__hip_atomic_load(&flg[(ig * 16 + tid) * 16], __ATOMIC_RELAXED,
                                          __HIP_MEMORY_SCOPE_AGENT) < t - 1)
                __builtin_amdgcn_s_sleep(1);
        }
        __syncthreads();
        asm volatile("" ::: "memory");

        const char* tb = srcA + (size_t)ig * 16 * 12288;
        GLDW(Wha, Wma, 0);
        GLDA3(ga0, ga1, ga2, 0);
        GLDA3(gb0, gb1, gb2, 1);
        asm volatile("s_waitcnt vmcnt(3)" ::: "memory");   // W0 + A0 done, A1 in flight
        DSWR3(0, ga0, ga1, ga2);
        asm volatile("s_waitcnt lgkmcnt(0)" ::: "memory");
        __builtin_amdgcn_s_barrier();
        DSRD7(0, 0);

        f32x4 acc0 = (f32x4){0.f, 0.f, 0.f, 0.f};
        f32x4 acc1 = (f32x4){0.f, 0.f, 0.f, 0.f};

        CHUNK_MID(0,  ga0, ga1, ga2, gb0, gb1, gb2, Wha, Wma, Whb, Wmb);
        CHUNK_MID(1,  gb0, gb1, gb2, ga0, ga1, ga2, Whb, Wmb, Wha, Wma);
        CHUNK_MID(2,  ga0, ga1, ga2, gb0, gb1, gb2, Wha, Wma, Whb, Wmb);
        CHUNK_MID(3,  gb0, gb1, gb2, ga0, ga1, ga2, Whb, Wmb, Wha, Wma);
        CHUNK_MID(4,  ga0, ga1, ga2, gb0, gb1, gb2, Wha, Wma, Whb, Wmb);
        CHUNK_MID(5,  gb0, gb1, gb2, ga0, ga1, ga2, Whb, Wmb, Wha, Wma);
        CHUNK_MID(6,  ga0, ga1, ga2, gb0, gb1, gb2, Wha, Wma, Whb, Wmb);
        CHUNK_MID(7,  gb0, gb1, gb2, ga0, ga1, ga2, Whb, Wmb, Wha, Wma);
        CHUNK_MID(8,  ga0, ga1, ga2, gb0, gb1, gb2, Wha, Wma, Whb, Wmb);
        CHUNK_MID(9,  gb0, gb1, gb2, ga0, ga1, ga2, Whb, Wmb, Wha, Wma);
        CHUNK_MID(10, ga0, ga1, ga2, gb0, gb1, gb2, Wha, Wma, Whb, Wmb);
        CHUNK_MID(11, gb0, gb1, gb2, ga0, ga1, ga2, Whb, Wmb, Wha, Wma);
        CHUNK_MID(12, ga0, ga1, ga2, gb0, gb1, gb2, Wha, Wma, Whb, Wmb);
        CHUNK_MID(13, gb0, gb1, gb2, ga0, ga1, ga2, Whb, Wmb, Wha, Wma);
        // c = 14: load W15, no A prefetch; drain and hand off chunk 15
        GLDW(Whb, Wmb, 15);
        MFMA12W(Wha, Wma);
        asm volatile("s_waitcnt vmcnt(0)" ::: "memory");
        DSWR3(1, gb0, gb1, gb2);
        asm volatile("s_waitcnt lgkmcnt(0)" ::: "memory");
        __builtin_amdgcn_s_barrier();
        DSRD7(1, 15);
        // c = 15
        MFMA12W(Whb, Wmb);

        __builtin_amdgcn_s_barrier();         // all waves done with A slots (red overlay)
        asm volatile("s_nop 7\n\ts_nop 7");   // MFMA->VALU read hazard guard

        // kh-pair reduction through LDS
#pragma unroll
        for (int r = 0; r < 4; ++r)
            red[w * 512 + (l4 * 4 + r) * 16 + l15] = acc0[r];
#pragma unroll
        for (int r = 0; r < 4; ++r)
            red[w * 512 + (16 + l4 * 4 + r) * 16 + l15] = acc1[r];
        __syncthreads();

        // epilogue: 4 outputs/thread, bias + mask + relu + exact re-split, coherent store
        {
            const int nqo = c4 >> 4, cl0 = c4 & 15;
            float4 p0 = *(const float4*)&red[(nqo * 2 + 0) * 512 + row * 16 + cl0];
            float4 p1 = *(const float4*)&red[(nqo * 2 + 1) * 512 + row * 16 + cl0];
            float s0 = p0.x + p1.x, s1 = p0.y + p1.y, s2 = p0.z + p1.z, s3 = p0.w + p1.w;
            const float* xt = X + (size_t)t * Vv;
            float u0 = s0 + bbv.x, u1 = s1 + bbv.y, u2 = s2 + bbv.z, u3 = s3 + bbv.w;
            if (js < 8) {
                int j0 = js * 64 + c4;
                float x0 = xt[j0], x1 = xt[j0 + 1], x2 = xt[j0 + 2], x3 = xt[j0 + 3];
                if (i_glob != j0)     u0 = 0.5f * u0 + 0.5f * x0;
                if (i_glob != j0 + 1) u1 = 0.5f * u1 + 0.5f * x1;
                if (i_glob != j0 + 2) u2 = 0.5f * u2 + 0.5f * x2;
                if (i_glob != j0 + 3) u3 = 0.5f * u3 + 0.5f * x3;
            }
            u0 = fmaxf(u0, 0.f); u1 = fmaxf(u1, 0.f);
            u2 = fmaxf(u2, 0.f); u3 = fmaxf(u3, 0.f);
            u16 h0, m0, l0, h1, m1, l1, h2, m2, l2, h3, m3, l3;
            split3(u0, h0, m0, l0); split3(u1, h1, m1, l1);
            split3(u2, h2, m2, l2); split3(u3, h3, m3, l3);
            u64 ph = (u64)h0 | ((u64)h1 << 16) | ((u64)h2 << 32) | ((u64)h3 << 48);
            u64 pm = (u64)m0 | ((u64)m1 << 16) | ((u64)m2 << 32) | ((u64)m3 << 48);
            u64 pl = (u64)l0 | ((u64)l1 << 16) | ((u64)l2 << 32) | ((u64)l3 << 48);
            size_t tbo = (size_t)(ig * 16 + js) * 12288
                       + (size_t)((c4 >> 3) * 32 + row) * 16 + (c4 & 7) * 2;
            GST(dstA + tbo, ph);
            GST(dstA + tbo + 4096, pm);
            GST(dstA + tbo + 8192, pl);
        }
        asm volatile("s_waitcnt vmcnt(0)" ::: "memory");
        __syncthreads();   // all waves' coherent stores drained
        if (tid == 0)
            __hip_atomic_store(&flg[(ig * 16 + js) * 16], (unsigned)t, __ATOMIC_RELAXED,
                               __HIP_MEMORY_SCOPE_AGENT);
    }
#undef GLDW
#undef GLDA3
#undef DSWR3
#undef DSRD7
#undef MFMA12W
#undef CHUNK_MID
}

// Final: out[i] = dot(R126[i,:], W[i,:]) + b[i]; R126 in A0 tiles (h+m+l exact)
__global__ void diag_kernel(const char* __restrict__ ws, const float* __restrict__ W,
                            const float* __restrict__ b, float* __restrict__ out) {
    int i = blockIdx.x, lane = threadIdx.x;
    const char* A0 = ws + OFF_A0;
    float s = 0.f;
#pragma unroll
    for (int rep = 0; rep < 2; ++rep) {
        int ko = lane + rep * 64;                 // k-octet 0..127
        int js = ko >> 3, o = ko & 7;
        size_t tb = (size_t)((i >> 5) * 16 + js) * 12288
                  + (size_t)(o * 32 + (i & 31)) * 16;
        s16x8 vh = *(const s16x8*)(A0 + tb);
        s16x8 vm = *(const s16x8*)(A0 + tb + 4096);
        s16x8 vl = *(const s16x8*)(A0 + tb + 8192);
        const float* wr = W + (size_t)i * Ff + ko * 8;
#pragma unroll
        for (int e = 0; e < 8; ++e)
            s += (bf2f(vh[e]) + bf2f(vm[e]) + bf2f(vl[e])) * wr[e];
    }
#pragma unroll
    for (int off = 32; off > 0; off >>= 1) s += __shfl_down(s, off);
    if (lane == 0) out[i] = s + b[i];
}

extern "C" void kernel_launch(void* const* d_in, const int* in_sizes, int n_in,
                              void* d_out, int out_size, void* d_ws, size_t ws_size,
                              hipStream_t stream) {
    const float* X = (const float*)d_in[0];   // (128, 512)
    const float* W = (const float*)d_in[1];   // (1024, 1024)
    const float* b = (const float*)d_in[2];   // (1024,)
    float* out = (float*)d_out;
    char* ws = (char*)d_ws;

    hipFuncSetAttribute(reinterpret_cast<const void*>(mega_kernel),
                        hipFuncAttributeMaxDynamicSharedMemorySize, 155648);

    wsplit_kernel<<<512, 256, 0, stream>>>(W, ws);
    init_kernel<<<256, 256, 0, stream>>>(X, b, ws);
    mega_kernel<<<256, 512, 155648, stream>>>(X, b, ws);
    diag_kernel<<<512, 64, 0, stream>>>(ws, W, b, out);
}

// Round 12
// 932.295 us; speedup vs baseline: 1.5623x; 1.5623x over previous
//
#include <hip/hip_runtime.h>
#include <stdint.h>

#define Vv 512
#define Ff 1024

typedef unsigned short u16;
typedef unsigned long long u64;
typedef __attribute__((ext_vector_type(8))) short s16x8;
typedef __attribute__((ext_vector_type(4))) float f32x4;

// workspace layout (bytes)
#define OFF_WH  (0ull)
#define OFF_WM  (2ull << 20)
#define OFF_WL  (4ull << 20)
#define OFF_A0  (6ull << 20)
#define OFF_A1  (9ull << 20)
#define OFF_FLG (12ull << 20)

// A buffer: 256 tiles (ig 16 x js 16), tile = 12288 B: [lv 3][o 8][r 32] 16B units;
// element (i=ig*32+r, j=js*64+o*8+e) at tile*12288 + lv*4096 + (o*32+r)*16 + e*2.

// Exact 3-way bf16 truncation split: v == h + m + l (bit-exact, 24 mantissa bits)
__device__ __forceinline__ void split3(float v, u16& h, u16& m, u16& l) {
    unsigned u = __float_as_uint(v);
    float fh = __uint_as_float(u & 0xFFFF0000u);
    h = (u16)(u >> 16);
    float r1 = v - fh;                         // exact
    unsigned u1 = __float_as_uint(r1);
    float fm = __uint_as_float(u1 & 0xFFFF0000u);
    m = (u16)(u1 >> 16);
    float r2 = r1 - fm;                        // exact
    l = (u16)(__float_as_uint(r2) >> 16);
}

__device__ __forceinline__ float bf2f(short v) {
    return __uint_as_float(((unsigned)(u16)v) << 16);
}

// W planes. Wh/Wm frag-major: unit = (((js*4+nq)*16+c)*2+kh)*64 + o*16 + col.
// Wl (per js-block 8192 units, LDS-linear): unit = js*8192 + (c*2+kh)*256 + o*64 + nq*16 + col.
__global__ void wsplit_kernel(const float* __restrict__ W, char* __restrict__ ws) {
    int idx = blockIdx.x * 256 + threadIdx.x;   // 0..131071 (j x k-octet)
    int j = idx >> 7, ko = idx & 127;
    const float* wr = W + (size_t)j * Ff + ko * 8;
    s16x8 vh, vm, vl;
#pragma unroll
    for (int e = 0; e < 8; ++e) {
        u16 h, m, l; split3(wr[e], h, m, l);
        vh[e] = (short)h; vm[e] = (short)m; vl[e] = (short)l;
    }
    int js = j >> 6, nq = (j >> 4) & 3, col = j & 15;
    int c = ko >> 3, kh = (ko >> 2) & 1, o = ko & 3;
    unsigned uhm = (unsigned)((((js * 4 + nq) * 16 + c) * 2 + kh) * 64 + o * 16 + col);
    unsigned ul  = (unsigned)(js * 8192 + (c * 2 + kh) * 256 + o * 64 + nq * 16 + col);
    *(s16x8*)(ws + OFF_WH + (size_t)uhm * 16) = vh;
    *(s16x8*)(ws + OFF_WM + (size_t)uhm * 16) = vm;
    *(s16x8*)(ws + OFF_WL + (size_t)ul * 16)  = vl;
}

// t=0 state into A0 tiles + zero the tile flags (64 B stride)
__global__ void init_kernel(const float* __restrict__ X, const float* __restrict__ b,
                            char* __restrict__ ws) {
    int idx = blockIdx.x * 256 + threadIdx.x;   // 0..65535 (i x j-octet)
    if (idx < 4096) ((unsigned*)(ws + OFF_FLG))[idx] = 0u;
    int i = idx >> 7, jo = idx & 127;
    s16x8 vh, vm, vl;
#pragma unroll
    for (int e = 0; e < 8; ++e) {
        int j = jo * 8 + e;
        float u = b[j];
        if (j < Vv && i != j) u = 0.5f * u + 0.5f * X[j];
        u = fmaxf(u, 0.f);
        u16 h, m, l; split3(u, h, m, l);
        vh[e] = (short)h; vm[e] = (short)m; vl[e] = (short)l;
    }
    int ig = i >> 5, r = i & 31, js = jo >> 3, o = jo & 7;
    size_t tb = (size_t)(ig * 16 + js) * 12288 + (size_t)(o * 32 + r) * 16;
    *(s16x8*)(ws + OFF_A0 + tb)        = vh;
    *(s16x8*)(ws + OFF_A0 + tb + 4096) = vm;
    *(s16x8*)(ws + OFF_A0 + tb + 8192) = vl;
}

#define GST(addr, val) \
    asm volatile("global_store_dwordx2 %0, %1, off sc0 sc1" \
                 :: "v"((void*)(addr)), "v"(val) : "memory")
#define MM(acc_, a_, b_) \
    asm("v_mfma_f32_16x16x32_bf16 %0, %1, %2, %0" : "+v"(acc_) : "v"(a_), "v"(b_))

// Persistent: 256 blocks x 512 thr; block = (ig, js). 8 waves: kh = w&1, nq = w>>1.
// Chunk order ROTATED: pipeline position n consumes tile cc=(js+n)&15, so chunk 0
// is the block's OWN tile -> staged from epilogue registers (no load, no flag wait),
// and the 16 consumers of an ig-group read 16 DIFFERENT tiles at any instant.
// 3-deep A prefetch (vmcnt(6)); per-wave flag poll overlapped with chunk 0 MFMA.
__global__ __launch_bounds__(512, 2)
void mega_kernel(const float* __restrict__ X, const float* __restrict__ b,
                 char* __restrict__ ws) {
    extern __shared__ char smem[];   // Wl 131072 | A slots 2x12288 (red overlays slots)
    const int tid = threadIdx.x, bid = blockIdx.x;
    const int ig = bid >> 4, js = bid & 15;
    const int lane = tid & 63, l15 = lane & 15, l4 = lane >> 4;
    const int w = tid >> 6, kh = w & 1, nq = w >> 1;

    unsigned* flg = (unsigned*)(ws + OFF_FLG);

    // one-time: Wl 64-col slice -> LDS (linear, async)
    {
        const char* src = ws + OFF_WL + (size_t)js * 131072;
#pragma unroll
        for (int q = 0; q < 16; ++q) {
            unsigned u = (unsigned)(q * 512 + tid) * 16u;
            __builtin_amdgcn_global_load_lds(
                (const __attribute__((address_space(1))) void*)(src + u),
                (__attribute__((address_space(3))) void*)(smem + u), 16, 0, 0);
        }
    }

    // one-time: Wh/Wm -> named register scalars, ROTATED by js (position n = tile (js+n)&15)
    s16x8 Bh0, Bh1, Bh2, Bh3, Bh4, Bh5, Bh6, Bh7, Bh8, Bh9, Bh10, Bh11, Bh12, Bh13, Bh14, Bh15;
    s16x8 Bm0, Bm1, Bm2, Bm3, Bm4, Bm5, Bm6, Bm7, Bm8, Bm9, Bm10, Bm11, Bm12, Bm13, Bm14, Bm15;
    {
        const char* wfrag = ws + OFF_WH +
            (size_t)(((((js * 4 + nq) * 16) * 2 + kh) * 64) + l4 * 16 + l15) * 16;
#define LOADW(n) do {                                                                  \
        const char* wp_ = wfrag + (size_t)(((js + (n)) & 15) * 2048);                  \
        asm volatile("global_load_dwordx4 %0, %1, off"                                 \
                     : "=v"(Bh##n) : "v"((const void*)wp_));                           \
        asm volatile("global_load_dwordx4 %0, %1, off"                                 \
                     : "=v"(Bm##n) : "v"((const void*)(wp_ + (2ull << 20))));          \
    } while (0)
        LOADW(0);  LOADW(1);  LOADW(2);  LOADW(3);
        LOADW(4);  LOADW(5);  LOADW(6);  LOADW(7);
        LOADW(8);  LOADW(9);  LOADW(10); LOADW(11);
        LOADW(12); LOADW(13); LOADW(14); LOADW(15);
#undef LOADW
    }

    const int row = tid >> 4, c4 = (tid & 15) * 4;
    const int i_glob = ig * 32 + row;
    const float4 bbv = *(const float4*)(b + js * 64 + c4);
    float* red = (float*)(smem + 131072);
    // epilogue/own-tile intra-tile byte offset (same formula as the global tile)
    const unsigned ownoff = (unsigned)(((c4 >> 3) * 32 + row) * 16 + (c4 & 7) * 2);

    // per-thread constant LDS offsets for fragment reads
    const unsigned abase = (unsigned)(((kh * 4 + l4) * 32 + l15) * 16);
    const unsigned a00 = abase,          a01 = abase + 256;             // lv0, mf0/1
    const unsigned a10 = abase + 4096,   a11 = abase + 4096 + 256;      // lv1
    const unsigned a20 = abase + 8192,   a21 = abase + 8192 + 256;      // lv2
    const unsigned bloff = (unsigned)(kh * 4096 + (l4 * 64 + nq * 16 + l15) * 16);

    s16x8 Af00, Af01, Af10, Af11, Af20, Af21, Bl;
    u64 ga0, ga1, ga2, gb0, gb1, gb2, gc0, gc1, gc2;

#define GLDA3(g0_, g1_, g2_, cc) do {                                                  \
        const char* ap_ = tb + (size_t)((cc) * 12288) + (size_t)tid * 8;               \
        asm volatile("global_load_dwordx2 %0, %1, off sc0 sc1"                         \
                     : "=v"(g0_) : "v"((const void*)ap_) : "memory");                  \
        asm volatile("global_load_dwordx2 %0, %1, off sc0 sc1"                         \
                     : "=v"(g1_) : "v"((const void*)(ap_ + 4096)) : "memory");         \
        asm volatile("global_load_dwordx2 %0, %1, off sc0 sc1"                         \
                     : "=v"(g2_) : "v"((const void*)(ap_ + 8192)) : "memory");         \
    } while (0)
#define DSWR3(slot, g0_, g1_, g2_) do {                                                \
        char* wp_ = smem + 131072 + (slot) * 12288 + (size_t)tid * 8;                  \
        *(u64*)(wp_) = g0_; *(u64*)(wp_ + 4096) = g1_; *(u64*)(wp_ + 8192) = g2_;      \
    } while (0)
#define DSRD7(slot, cc) do {                                                           \
        const char* sb_ = smem + 131072 + (slot) * 12288;                              \
        Af00 = *(const s16x8*)(sb_ + a00); Af01 = *(const s16x8*)(sb_ + a01);          \
        Af10 = *(const s16x8*)(sb_ + a10); Af11 = *(const s16x8*)(sb_ + a11);          \
        Af20 = *(const s16x8*)(sb_ + a20); Af21 = *(const s16x8*)(sb_ + a21);          \
        Bl = *(const s16x8*)(smem + (size_t)((cc) * 8192) + bloff);                    \
    } while (0)
#define MFMA12(n) do {                                                                 \
        __builtin_amdgcn_s_setprio(1);                                                 \
        MM(acc0, Af00, Bh##n); MM(acc1, Af01, Bh##n);                                  \
        MM(acc0, Af00, Bm##n); MM(acc1, Af01, Bm##n);                                  \
        MM(acc0, Af10, Bh##n); MM(acc1, Af11, Bh##n);                                  \
        MM(acc0, Af00, Bl);    MM(acc1, Af01, Bl);                                     \
        MM(acc0, Af20, Bh##n); MM(acc1, Af21, Bh##n);                                  \
        MM(acc0, Af10, Bm##n); MM(acc1, Af11, Bm##n);                                  \
        __builtin_amdgcn_s_setprio(0);                                                 \
    } while (0)
// chunk n in [0..12]: issue tile (n+3) into set n%3, compute n, hand off n+1 from set (n+1)%3
#define CHUNK(n, P0, P1, P2, Q0, Q1, Q2, VM) do {                                      \
        __builtin_amdgcn_sched_barrier(0);                                             \
        MFMA12(n);                                                                     \
        __builtin_amdgcn_sched_barrier(0);                                             \
        asm volatile("s_waitcnt vmcnt(" #VM ")" ::: "memory");                         \
        DSWR3(((n) + 1) & 1, Q0, Q1, Q2);                                              \
        asm volatile("s_waitcnt lgkmcnt(0)" ::: "memory");                             \
        __builtin_amdgcn_s_barrier();                                                  \
        DSRD7(((n) + 1) & 1, (js + (n) + 1) & 15);                                     \
    } while (0)

    // prologue: own tile of step-1 input (A0, written by init_kernel) -> slot 0
    {
        const char* own0 = ws + OFF_A0 + (size_t)(ig * 16 + js) * 12288;
        const char* tb = own0;   // GLDA3 uses tb + cc*12288 with cc=0
        GLDA3(ga0, ga1, ga2, 0);
        asm volatile("s_waitcnt vmcnt(0)" ::: "memory");
        DSWR3(0, ga0, ga1, ga2);
    }
    __syncthreads();   // Wl + W regs + slot0 ready (drains vmcnt/lgkmcnt)

    for (int t = 1; t <= 126; ++t) {
        char* srcA = ws + ((t & 1) ? OFF_A0 : OFF_A1);
        char* dstA = ws + ((t & 1) ? OFF_A1 : OFF_A0);
        const char* tb = srcA + (size_t)ig * 16 * 12288;

        // chunk 0 fragments come from our own slot-0 staging — no flag, no load
        DSRD7(0, js);

        // per-wave poll for the 15 foreign producer tiles (lanes 0..15, no block sync)
        if (lane < 16) {
            while ((int)__hip_atomic_load(&flg[(ig * 16 + lane) * 16], __ATOMIC_RELAXED,
                                          __HIP_MEMORY_SCOPE_AGENT) < t - 1)
                __builtin_amdgcn_s_sleep(1);
        }
        asm volatile("" ::: "memory");

        // 3-deep prefetch: tiles at positions 1,2 (position 3 issued inside chunk 0)
        GLDA3(gb0, gb1, gb2, (js + 1) & 15);
        GLDA3(gc0, gc1, gc2, (js + 2) & 15);

        f32x4 acc0 = (f32x4){0.f, 0.f, 0.f, 0.f};
        f32x4 acc1 = (f32x4){0.f, 0.f, 0.f, 0.f};

        GLDA3(ga0, ga1, ga2, (js + 3) & 15);
        CHUNK(0,  ga0, ga1, ga2, gb0, gb1, gb2, 6);
        GLDA3(gb0, gb1, gb2, (js + 4) & 15);
        CHUNK(1,  gb0, gb1, gb2, gc0, gc1, gc2, 6);
        GLDA3(gc0, gc1, gc2, (js + 5) & 15);
        CHUNK(2,  gc0, gc1, gc2, ga0, ga1, ga2, 6);
        GLDA3(ga0, ga1, ga2, (js + 6) & 15);
        CHUNK(3,  ga0, ga1, ga2, gb0, gb1, gb2, 6);
        GLDA3(gb0, gb1, gb2, (js + 7) & 15);
        CHUNK(4,  gb0, gb1, gb2, gc0, gc1, gc2, 6);
        GLDA3(gc0, gc1, gc2, (js + 8) & 15);
        CHUNK(5,  gc0, gc1, gc2, ga0, ga1, ga2, 6);
        GLDA3(ga0, ga1, ga2, (js + 9) & 15);
        CHUNK(6,  ga0, ga1, ga2, gb0, gb1, gb2, 6);
        GLDA3(gb0, gb1, gb2, (js + 10) & 15);
        CHUNK(7,  gb0, gb1, gb2, gc0, gc1, gc2, 6);
        GLDA3(gc0, gc1, gc2, (js + 11) & 15);
        CHUNK(8,  gc0, gc1, gc2, ga0, ga1, ga2, 6);
        GLDA3(ga0, ga1, ga2, (js + 12) & 15);
        CHUNK(9,  ga0, ga1, ga2, gb0, gb1, gb2, 6);
        GLDA3(gb0, gb1, gb2, (js + 13) & 15);
        CHUNK(10, gb0, gb1, gb2, gc0, gc1, gc2, 6);
        GLDA3(gc0, gc1, gc2, (js + 14) & 15);
        CHUNK(11, gc0, gc1, gc2, ga0, ga1, ga2, 6);
        GLDA3(ga0, ga1, ga2, (js + 15) & 15);
        CHUNK(12, ga0, ga1, ga2, gb0, gb1, gb2, 6);
        CHUNK(13, ga0, ga1, ga2, gc0, gc1, gc2, 3);   // no issue; wait set14
        CHUNK(14, ga0, ga1, ga2, ga0, ga1, ga2, 0);   // no issue; wait set15
        MFMA12(15);

        __builtin_amdgcn_s_barrier();         // all waves done with A slots (red overlay)
        asm volatile("s_nop 7\n\ts_nop 7");   // MFMA->VALU read hazard guard

        // kh-pair reduction through LDS
#pragma unroll
        for (int r = 0; r < 4; ++r)
            red[w * 512 + (l4 * 4 + r) * 16 + l15] = acc0[r];
#pragma unroll
        for (int r = 0; r < 4; ++r)
            red[w * 512 + (16 + l4 * 4 + r) * 16 + l15] = acc1[r];
        __syncthreads();

        // read partials, then a barrier before the own-tile LDS overwrite (WAR)
        const int nqo = c4 >> 4, cl0 = c4 & 15;
        float4 p0 = *(const float4*)&red[(nqo * 2 + 0) * 512 + row * 16 + cl0];
        float4 p1 = *(const float4*)&red[(nqo * 2 + 1) * 512 + row * 16 + cl0];
        __syncthreads();

        // epilogue: bias + mask + relu + exact re-split; store to global AND slot 0
        {
            float s0 = p0.x + p1.x, s1 = p0.y + p1.y, s2 = p0.z + p1.z, s3 = p0.w + p1.w;
            const float* xt = X + (size_t)t * Vv;
            float u0 = s0 + bbv.x, u1 = s1 + bbv.y, u2 = s2 + bbv.z, u3 = s3 + bbv.w;
            if (js < 8) {
                int j0 = js * 64 + c4;
                float x0 = xt[j0], x1 = xt[j0 + 1], x2 = xt[j0 + 2], x3 = xt[j0 + 3];
                if (i_glob != j0)     u0 = 0.5f * u0 + 0.5f * x0;
                if (i_glob != j0 + 1) u1 = 0.5f * u1 + 0.5f * x1;
                if (i_glob != j0 + 2) u2 = 0.5f * u2 + 0.5f * x2;
                if (i_glob != j0 + 3) u3 = 0.5f * u3 + 0.5f * x3;
            }
            u0 = fmaxf(u0, 0.f); u1 = fmaxf(u1, 0.f);
            u2 = fmaxf(u2, 0.f); u3 = fmaxf(u3, 0.f);
            u16 h0, m0, l0, h1, m1, l1, h2, m2, l2, h3, m3, l3;
            split3(u0, h0, m0, l0); split3(u1, h1, m1, l1);
            split3(u2, h2, m2, l2); split3(u3, h3, m3, l3);
            u64 ph = (u64)h0 | ((u64)h1 << 16) | ((u64)h2 << 32) | ((u64)h3 << 48);
            u64 pm = (u64)m0 | ((u64)m1 << 16) | ((u64)m2 << 32) | ((u64)m3 << 48);
            u64 pl = (u64)l0 | ((u64)l1 << 16) | ((u64)l2 << 32) | ((u64)l3 << 48);
            size_t tbo = (size_t)(ig * 16 + js) * 12288 + ownoff;
            GST(dstA + tbo, ph);
            GST(dstA + tbo + 4096, pm);
            GST(dstA + tbo + 8192, pl);
            // own tile -> slot 0 for next step (no reload needed)
            *(u64*)(smem + 131072 + ownoff) = ph;
            *(u64*)(smem + 131072 + ownoff + 4096) = pm;
            *(u64*)(smem + 131072 + ownoff + 8192) = pl;
        }
        asm volatile("s_waitcnt vmcnt(0)" ::: "memory");
        __syncthreads();   // stores drained + slot0 staged
        if (tid == 0)
            __hip_atomic_store(&flg[(ig * 16 + js) * 16], (unsigned)t, __ATOMIC_RELAXED,
                               __HIP_MEMORY_SCOPE_AGENT);
    }
#undef GLDA3
#undef DSWR3
#undef DSRD7
#undef MFMA12
#undef CHUNK
}

// Final: out[i] = dot(R126[i,:], W[i,:]) + b[i]; R126 in A0 tiles (h+m+l exact)
__global__ void diag_kernel(const char* __restrict__ ws, const float* __restrict__ W,
                            const float* __restrict__ b, float* __restrict__ out) {
    int i = blockIdx.x, lane = threadIdx.x;
    const char* A0 = ws + OFF_A0;
    float s = 0.f;
#pragma unroll
    for (int rep = 0; rep < 2; ++rep) {
        int ko = lane + rep * 64;                 // k-octet 0..127
        int js = ko >> 3, o = ko & 7;
        size_t tb = (size_t)((i >> 5) * 16 + js) * 12288
                  + (size_t)(o * 32 + (i & 31)) * 16;
        s16x8 vh = *(const s16x8*)(A0 + tb);
        s16x8 vm = *(const s16x8*)(A0 + tb + 4096);
        s16x8 vl = *(const s16x8*)(A0 + tb + 8192);
        const float* wr = W + (size_t)i * Ff + ko * 8;
#pragma unroll
        for (int e = 0; e < 8; ++e)
            s += (bf2f(vh[e]) + bf2f(vm[e]) + bf2f(vl[e])) * wr[e];
    }
#pragma unroll
    for (int off = 32; off > 0; off >>= 1) s += __shfl_down(s, off);
    if (lane == 0) out[i] = s + b[i];
}

extern "C" void kernel_launch(void* const* d_in, const int* in_sizes, int n_in,
                              void* d_out, int out_size, void* d_ws, size_t ws_size,
                              hipStream_t stream) {
    const float* X = (const float*)d_in[0];   // (128, 512)
    const float* W = (const float*)d_in[1];   // (1024, 1024)
    const float* b = (const float*)d_in[2];   // (1024,)
    float* out = (float*)d_out;
    char* ws = (char*)d_ws;

    hipFuncSetAttribute(reinterpret_cast<const void*>(mega_kernel),
                        hipFuncAttributeMaxDynamicSharedMemorySize, 155648);

    wsplit_kernel<<<512, 256, 0, stream>>>(W, ws);
    init_kernel<<<256, 256, 0, stream>>>(X, b, ws);
    mega_kernel<<<256, 512, 155648, stream>>>(X, b, ws);
    diag_kernel<<<512, 64, 0, stream>>>(ws, W, b, out);
}

// Round 15
// 931.855 us; speedup vs baseline: 1.5631x; 1.0005x over previous
//
#include <hip/hip_runtime.h>
#include <stdint.h>

#define Vv 512
#define Ff 1024

typedef unsigned short u16;
typedef unsigned long long u64;
typedef __attribute__((ext_vector_type(8))) short s16x8;
typedef __attribute__((ext_vector_type(4))) float f32x4;

// workspace layout (bytes)
#define OFF_WH  (0ull)
#define OFF_WM  (2ull << 20)
#define OFF_WL  (4ull << 20)
#define OFF_A0  (6ull << 20)
#define OFF_A1  (9ull << 20)
#define OFF_FLG (12ull << 20)

// A buffer: 256 tiles (ig 16 x js 16), tile = 12288 B: [lv 3][o 8][r 32] 16B units;
// element (i=ig*32+r, j=js*64+o*8+e) at tile*12288 + lv*4096 + (o*32+r)*16 + e*2.

// Exact 3-way bf16 truncation split: v == h + m + l (bit-exact, 24 mantissa bits)
__device__ __forceinline__ void split3(float v, u16& h, u16& m, u16& l) {
    unsigned u = __float_as_uint(v);
    float fh = __uint_as_float(u & 0xFFFF0000u);
    h = (u16)(u >> 16);
    float r1 = v - fh;                         // exact
    unsigned u1 = __float_as_uint(r1);
    float fm = __uint_as_float(u1 & 0xFFFF0000u);
    m = (u16)(u1 >> 16);
    float r2 = r1 - fm;                        // exact
    l = (u16)(__float_as_uint(r2) >> 16);
}

__device__ __forceinline__ float bf2f(short v) {
    return __uint_as_float(((unsigned)(u16)v) << 16);
}

// W planes. Wh/Wm frag-major: unit = (((js*4+nq)*16+c)*2+kh)*64 + o*16 + col.
// Wl (per js-block 8192 units, LDS-linear): unit = js*8192 + (c*2+kh)*256 + o*64 + nq*16 + col.
__global__ void wsplit_kernel(const float* __restrict__ W, char* __restrict__ ws) {
    int idx = blockIdx.x * 256 + threadIdx.x;   // 0..131071 (j x k-octet)
    int j = idx >> 7, ko = idx & 127;
    const float* wr = W + (size_t)j * Ff + ko * 8;
    s16x8 vh, vm, vl;
#pragma unroll
    for (int e = 0; e < 8; ++e) {
        u16 h, m, l; split3(wr[e], h, m, l);
        vh[e] = (short)h; vm[e] = (short)m; vl[e] = (short)l;
    }
    int js = j >> 6, nq = (j >> 4) & 3, col = j & 15;
    int c = ko >> 3, kh = (ko >> 2) & 1, o = ko & 3;
    unsigned uhm = (unsigned)((((js * 4 + nq) * 16 + c) * 2 + kh) * 64 + o * 16 + col);
    unsigned ul  = (unsigned)(js * 8192 + (c * 2 + kh) * 256 + o * 64 + nq * 16 + col);
    *(s16x8*)(ws + OFF_WH + (size_t)uhm * 16) = vh;
    *(s16x8*)(ws + OFF_WM + (size_t)uhm * 16) = vm;
    *(s16x8*)(ws + OFF_WL + (size_t)ul * 16)  = vl;
}

// t=0 state into A0 tiles + zero the tile flags (64 B stride)
__global__ void init_kernel(const float* __restrict__ X, const float* __restrict__ b,
                            char* __restrict__ ws) {
    int idx = blockIdx.x * 256 + threadIdx.x;   // 0..65535 (i x j-octet)
    if (idx < 4096) ((unsigned*)(ws + OFF_FLG))[idx] = 0u;
    int i = idx >> 7, jo = idx & 127;
    s16x8 vh, vm, vl;
#pragma unroll
    for (int e = 0; e < 8; ++e) {
        int j = jo * 8 + e;
        float u = b[j];
        if (j < Vv && i != j) u = 0.5f * u + 0.5f * X[j];
        u = fmaxf(u, 0.f);
        u16 h, m, l; split3(u, h, m, l);
        vh[e] = (short)h; vm[e] = (short)m; vl[e] = (short)l;
    }
    int ig = i >> 5, r = i & 31, js = jo >> 3, o = jo & 7;
    size_t tb = (size_t)(ig * 16 + js) * 12288 + (size_t)(o * 32 + r) * 16;
    *(s16x8*)(ws + OFF_A0 + tb)        = vh;
    *(s16x8*)(ws + OFF_A0 + tb + 4096) = vm;
    *(s16x8*)(ws + OFF_A0 + tb + 8192) = vl;
}

#define GST(addr, val) \
    asm volatile("global_store_dwordx2 %0, %1, off sc0 sc1" \
                 :: "v"((void*)(addr)), "v"(val) : "memory")
#define MM(acc_, a_, b_) \
    asm("v_mfma_f32_16x16x32_bf16 %0, %1, %2, %0" : "+v"(acc_) : "v"(a_), "v"(b_))

// Persistent: 256 blocks x 512 thr; block = (ig, js). 8 waves: kh = w&1, nq = w>>1.
// Chunk order ROTATED: pipeline position n consumes tile cc=(js+n)&15, so chunk 0
// is the block's OWN tile -> staged from epilogue registers (no load, no flag wait),
// and the 16 consumers of an ig-group read 16 DIFFERENT tiles at any instant.
// 3-deep A prefetch (vmcnt(6)); per-wave flag poll overlapped with chunk 0 MFMA.
__global__ __launch_bounds__(512, 2)
void mega_kernel(const float* __restrict__ X, const float* __restrict__ b,
                 char* __restrict__ ws) {
    extern __shared__ char smem[];   // Wl 131072 | A slots 2x12288 (red overlays slots)
    const int tid = threadIdx.x, bid = blockIdx.x;
    const int ig = bid >> 4, js = bid & 15;
    const int lane = tid & 63, l15 = lane & 15, l4 = lane >> 4;
    const int w = tid >> 6, kh = w & 1, nq = w >> 1;

    unsigned* flg = (unsigned*)(ws + OFF_FLG);

    // one-time: Wl 64-col slice -> LDS (linear, async)
    {
        const char* src = ws + OFF_WL + (size_t)js * 131072;
#pragma unroll
        for (int q = 0; q < 16; ++q) {
            unsigned u = (unsigned)(q * 512 + tid) * 16u;
            __builtin_amdgcn_global_load_lds(
                (const __attribute__((address_space(1))) void*)(src + u),
                (__attribute__((address_space(3))) void*)(smem + u), 16, 0, 0);
        }
    }

    // one-time: Wh/Wm -> named register scalars, ROTATED by js (position n = tile (js+n)&15)
    s16x8 Bh0, Bh1, Bh2, Bh3, Bh4, Bh5, Bh6, Bh7, Bh8, Bh9, Bh10, Bh11, Bh12, Bh13, Bh14, Bh15;
    s16x8 Bm0, Bm1, Bm2, Bm3, Bm4, Bm5, Bm6, Bm7, Bm8, Bm9, Bm10, Bm11, Bm12, Bm13, Bm14, Bm15;
    {
        const char* wfrag = ws + OFF_WH +
            (size_t)(((((js * 4 + nq) * 16) * 2 + kh) * 64) + l4 * 16 + l15) * 16;
#define LOADW(n) do {                                                                  \
        const char* wp_ = wfrag + (size_t)(((js + (n)) & 15) * 2048);                  \
        asm volatile("global_load_dwordx4 %0, %1, off"                                 \
                     : "=v"(Bh##n) : "v"((const void*)wp_));                           \
        asm volatile("global_load_dwordx4 %0, %1, off"                                 \
                     : "=v"(Bm##n) : "v"((const void*)(wp_ + (2ull << 20))));          \
    } while (0)
        LOADW(0);  LOADW(1);  LOADW(2);  LOADW(3);
        LOADW(4);  LOADW(5);  LOADW(6);  LOADW(7);
        LOADW(8);  LOADW(9);  LOADW(10); LOADW(11);
        LOADW(12); LOADW(13); LOADW(14); LOADW(15);
#undef LOADW
    }

    const int row = tid >> 4, c4 = (tid & 15) * 4;
    const int i_glob = ig * 32 + row;
    const float4 bbv = *(const float4*)(b + js * 64 + c4);
    float* red = (float*)(smem + 131072);
    // epilogue/own-tile intra-tile byte offset (same formula as the global tile)
    const unsigned ownoff = (unsigned)(((c4 >> 3) * 32 + row) * 16 + (c4 & 7) * 2);

    // per-thread constant LDS offsets for fragment reads
    const unsigned abase = (unsigned)(((kh * 4 + l4) * 32 + l15) * 16);
    const unsigned a00 = abase,          a01 = abase + 256;             // lv0, mf0/1
    const unsigned a10 = abase + 4096,   a11 = abase + 4096 + 256;      // lv1
    const unsigned a20 = abase + 8192,   a21 = abase + 8192 + 256;      // lv2
    const unsigned bloff = (unsigned)(kh * 4096 + (l4 * 64 + nq * 16 + l15) * 16);

    s16x8 Af00, Af01, Af10, Af11, Af20, Af21, Bl;
    u64 ga0, ga1, ga2, gb0, gb1, gb2, gc0, gc1, gc2;

#define GLDA3(g0_, g1_, g2_, cc) do {                                                  \
        const char* ap_ = tb + (size_t)((cc) * 12288) + (size_t)tid * 8;               \
        asm volatile("global_load_dwordx2 %0, %1, off sc0 sc1"                         \
                     : "=v"(g0_) : "v"((const void*)ap_) : "memory");                  \
        asm volatile("global_load_dwordx2 %0, %1, off sc0 sc1"                         \
                     : "=v"(g1_) : "v"((const void*)(ap_ + 4096)) : "memory");         \
        asm volatile("global_load_dwordx2 %0, %1, off sc0 sc1"                         \
                     : "=v"(g2_) : "v"((const void*)(ap_ + 8192)) : "memory");         \
    } while (0)
#define DSWR3(slot, g0_, g1_, g2_) do {                                                \
        char* wp_ = smem + 131072 + (slot) * 12288 + (size_t)tid * 8;                  \
        *(u64*)(wp_) = g0_; *(u64*)(wp_ + 4096) = g1_; *(u64*)(wp_ + 8192) = g2_;      \
    } while (0)
#define DSRD7(slot, cc) do {                                                           \
        const char* sb_ = smem + 131072 + (slot) * 12288;                              \
        Af00 = *(const s16x8*)(sb_ + a00); Af01 = *(const s16x8*)(sb_ + a01);          \
        Af10 = *(const s16x8*)(sb_ + a10); Af11 = *(const s16x8*)(sb_ + a11);          \
        Af20 = *(const s16x8*)(sb_ + a20); Af21 = *(const s16x8*)(sb_ + a21);          \
        Bl = *(const s16x8*)(smem + (size_t)((cc) * 8192) + bloff);                    \
    } while (0)
#define MFMA12(n) do {                                                                 \
        __builtin_amdgcn_s_setprio(1);                                                 \
        MM(acc0, Af00, Bh##n); MM(acc1, Af01, Bh##n);                                  \
        MM(acc0, Af00, Bm##n); MM(acc1, Af01, Bm##n);                                  \
        MM(acc0, Af10, Bh##n); MM(acc1, Af11, Bh##n);                                  \
        MM(acc0, Af00, Bl);    MM(acc1, Af01, Bl);                                     \
        MM(acc0, Af20, Bh##n); MM(acc1, Af21, Bh##n);                                  \
        MM(acc0, Af10, Bm##n); MM(acc1, Af11, Bm##n);                                  \
        __builtin_amdgcn_s_setprio(0);                                                 \
    } while (0)
// chunk n in [0..12]: issue tile (n+3) into set n%3, compute n, hand off n+1 from set (n+1)%3
#define CHUNK(n, P0, P1, P2, Q0, Q1, Q2, VM) do {                                      \
        __builtin_amdgcn_sched_barrier(0);                                             \
        MFMA12(n);                                                                     \
        __builtin_amdgcn_sched_barrier(0);                                             \
        asm volatile("s_waitcnt vmcnt(" #VM ")" ::: "memory");                         \
        DSWR3(((n) + 1) & 1, Q0, Q1, Q2);                                              \
        asm volatile("s_waitcnt lgkmcnt(0)" ::: "memory");                             \
        __builtin_amdgcn_s_barrier();                                                  \
        DSRD7(((n) + 1) & 1, (js + (n) + 1) & 15);                                     \
    } while (0)

    // prologue: own tile of step-1 input (A0, written by init_kernel) -> slot 0
    {
        const char* own0 = ws + OFF_A0 + (size_t)(ig * 16 + js) * 12288;
        const char* tb = own0;   // GLDA3 uses tb + cc*12288 with cc=0
        GLDA3(ga0, ga1, ga2, 0);
        asm volatile("s_waitcnt vmcnt(0)" ::: "memory");
        DSWR3(0, ga0, ga1, ga2);
    }
    __syncthreads();   // Wl + W regs + slot0 ready (drains vmcnt/lgkmcnt)

    for (int t = 1; t <= 126; ++t) {
        char* srcA = ws + ((t & 1) ? OFF_A0 : OFF_A1);
        char* dstA = ws + ((t & 1) ? OFF_A1 : OFF_A0);
        const char* tb = srcA + (size_t)ig * 16 * 12288;

        // chunk 0 fragments come from our own slot-0 staging — no flag, no load
        DSRD7(0, js);

        // per-wave poll for the 15 foreign producer tiles (lanes 0..15, no block sync)
        if (lane < 16) {
            while ((int)__hip_atomic_load(&flg[(ig * 16 + lane) * 16], __ATOMIC_RELAXED,
                                          __HIP_MEMORY_SCOPE_AGENT) < t - 1)
                __builtin_amdgcn_s_sleep(1);
        }
        asm volatile("" ::: "memory");

        // 3-deep prefetch: tiles at positions 1,2 (position 3 issued inside chunk 0)
        GLDA3(gb0, gb1, gb2, (js + 1) & 15);
        GLDA3(gc0, gc1, gc2, (js + 2) & 15);

        f32x4 acc0 = (f32x4){0.f, 0.f, 0.f, 0.f};
        f32x4 acc1 = (f32x4){0.f, 0.f, 0.f, 0.f};

        GLDA3(ga0, ga1, ga2, (js + 3) & 15);
        CHUNK(0,  ga0, ga1, ga2, gb0, gb1, gb2, 6);
        GLDA3(gb0, gb1, gb2, (js + 4) & 15);
        CHUNK(1,  gb0, gb1, gb2, gc0, gc1, gc2, 6);
        GLDA3(gc0, gc1, gc2, (js + 5) & 15);
        CHUNK(2,  gc0, gc1, gc2, ga0, ga1, ga2, 6);
        GLDA3(ga0, ga1, ga2, (js + 6) & 15);
        CHUNK(3,  ga0, ga1, ga2, gb0, gb1, gb2, 6);
        GLDA3(gb0, gb1, gb2, (js + 7) & 15);
        CHUNK(4,  gb0, gb1, gb2, gc0, gc1, gc2, 6);
        GLDA3(gc0, gc1, gc2, (js + 8) & 15);
        CHUNK(5,  gc0, gc1, gc2, ga0, ga1, ga2, 6);
        GLDA3(ga0, ga1, ga2, (js + 9) & 15);
        CHUNK(6,  ga0, ga1, ga2, gb0, gb1, gb2, 6);
        GLDA3(gb0, gb1, gb2, (js + 10) & 15);
        CHUNK(7,  gb0, gb1, gb2, gc0, gc1, gc2, 6);
        GLDA3(gc0, gc1, gc2, (js + 11) & 15);
        CHUNK(8,  gc0, gc1, gc2, ga0, ga1, ga2, 6);
        GLDA3(ga0, ga1, ga2, (js + 12) & 15);
        CHUNK(9,  ga0, ga1, ga2, gb0, gb1, gb2, 6);
        GLDA3(gb0, gb1, gb2, (js + 13) & 15);
        CHUNK(10, gb0, gb1, gb2, gc0, gc1, gc2, 6);
        GLDA3(gc0, gc1, gc2, (js + 14) & 15);
        CHUNK(11, gc0, gc1, gc2, ga0, ga1, ga2, 6);
        GLDA3(ga0, ga1, ga2, (js + 15) & 15);
        CHUNK(12, ga0, ga1, ga2, gb0, gb1, gb2, 6);
        CHUNK(13, ga0, ga1, ga2, gc0, gc1, gc2, 3);   // no issue; wait set14
        CHUNK(14, ga0, ga1, ga2, ga0, ga1, ga2, 0);   // no issue; wait set15
        MFMA12(15);

        __builtin_amdgcn_s_barrier();         // all waves done with A slots (red overlay)
        asm volatile("s_nop 7\n\ts_nop 7");   // MFMA->VALU read hazard guard

        // kh-pair reduction through LDS
#pragma unroll
        for (int r = 0; r < 4; ++r)
            red[w * 512 + (l4 * 4 + r) * 16 + l15] = acc0[r];
#pragma unroll
        for (int r = 0; r < 4; ++r)
            red[w * 512 + (16 + l4 * 4 + r) * 16 + l15] = acc1[r];
        __syncthreads();

        // read partials, then a barrier before the own-tile LDS overwrite (WAR)
        const int nqo = c4 >> 4, cl0 = c4 & 15;
        float4 p0 = *(const float4*)&red[(nqo * 2 + 0) * 512 + row * 16 + cl0];
        float4 p1 = *(const float4*)&red[(nqo * 2 + 1) * 512 + row * 16 + cl0];
        __syncthreads();

        // epilogue: bias + mask + relu + exact re-split; store to global AND slot 0
        {
            float s0 = p0.x + p1.x, s1 = p0.y + p1.y, s2 = p0.z + p1.z, s3 = p0.w + p1.w;
            const float* xt = X + (size_t)t * Vv;
            float u0 = s0 + bbv.x, u1 = s1 + bbv.y, u2 = s2 + bbv.z, u3 = s3 + bbv.w;
            if (js < 8) {
                int j0 = js * 64 + c4;
                float x0 = xt[j0], x1 = xt[j0 + 1], x2 = xt[j0 + 2], x3 = xt[j0 + 3];
                if (i_glob != j0)     u0 = 0.5f * u0 + 0.5f * x0;
                if (i_glob != j0 + 1) u1 = 0.5f * u1 + 0.5f * x1;
                if (i_glob != j0 + 2) u2 = 0.5f * u2 + 0.5f * x2;
                if (i_glob != j0 + 3) u3 = 0.5f * u3 + 0.5f * x3;
            }
            u0 = fmaxf(u0, 0.f); u1 = fmaxf(u1, 0.f);
            u2 = fmaxf(u2, 0.f); u3 = fmaxf(u3, 0.f);
            u16 h0, m0, l0, h1, m1, l1, h2, m2, l2, h3, m3, l3;
            split3(u0, h0, m0, l0); split3(u1, h1, m1, l1);
            split3(u2, h2, m2, l2); split3(u3, h3, m3, l3);
            u64 ph = (u64)h0 | ((u64)h1 << 16) | ((u64)h2 << 32) | ((u64)h3 << 48);
            u64 pm = (u64)m0 | ((u64)m1 << 16) | ((u64)m2 << 32) | ((u64)m3 << 48);
            u64 pl = (u64)l0 | ((u64)l1 << 16) | ((u64)l2 << 32) | ((u64)l3 << 48);
            size_t tbo = (size_t)(ig * 16 + js) * 12288 + ownoff;
            GST(dstA + tbo, ph);
            GST(dstA + tbo + 4096, pm);
            GST(dstA + tbo + 8192, pl);
            // own tile -> slot 0 for next step (no reload needed)
            *(u64*)(smem + 131072 + ownoff) = ph;
            *(u64*)(smem + 131072 + ownoff + 4096) = pm;
            *(u64*)(smem + 131072 + ownoff + 8192) = pl;
        }
        asm volatile("s_waitcnt vmcnt(0)" ::: "memory");
        __syncthreads();   // stores drained + slot0 staged
        if (tid == 0)
            __hip_atomic_store(&flg[(ig * 16 + js) * 16], (unsigned)t, __ATOMIC_RELAXED,
                               __HIP_MEMORY_SCOPE_AGENT);
    }
#undef GLDA3
#undef DSWR3
#undef DSRD7
#undef MFMA12
#undef CHUNK
}

// Final: out[i] = dot(R126[i,:], W[i,:]) + b[i]; R126 in A0 tiles (h+m+l exact)
__global__ void diag_kernel(const char* __restrict__ ws, const float* __restrict__ W,
                            const float* __restrict__ b, float* __restrict__ out) {
    int i = blockIdx.x, lane = threadIdx.x;
    const char* A0 = ws + OFF_A0;
    float s = 0.f;
#pragma unroll
    for (int rep = 0; rep < 2; ++rep) {
        int ko = lane + rep * 64;                 // k-octet 0..127
        int js = ko >> 3, o = ko & 7;
        size_t tb = (size_t)((i >> 5) * 16 + js) * 12288
                  + (size_t)(o * 32 + (i & 31)) * 16;
        s16x8 vh = *(const s16x8*)(A0 + tb);
        s16x8 vm = *(const s16x8*)(A0 + tb + 4096);
        s16x8 vl = *(const s16x8*)(A0 + tb + 8192);
        const float* wr = W + (size_t)i * Ff + ko * 8;
#pragma unroll
        for (int e = 0; e < 8; ++e)
            s += (bf2f(vh[e]) + bf2f(vm[e]) + bf2f(vl[e])) * wr[e];
    }
#pragma unroll
    for (int off = 32; off > 0; off >>= 1) s += __shfl_down(s, off);
    if (lane == 0) out[i] = s + b[i];
}

extern "C" void kernel_launch(void* const* d_in, const int* in_sizes, int n_in,
                              void* d_out, int out_size, void* d_ws, size_t ws_size,
                              hipStream_t stream) {
    const float* X = (const float*)d_in[0];   // (128, 512)
    const float* W = (const float*)d_in[1];   // (1024, 1024)
    const float* b = (const float*)d_in[2];   // (1024,)
    float* out = (float*)d_out;
    char* ws = (char*)d_ws;

    hipFuncSetAttribute(reinterpret_cast<const void*>(mega_kernel),
                        hipFuncAttributeMaxDynamicSharedMemorySize, 155648);

    wsplit_kernel<<<512, 256, 0, stream>>>(W, ws);
    init_kernel<<<256, 256, 0, stream>>>(X, b, ws);
    mega_kernel<<<256, 512, 155648, stream>>>(X, b, ws);
    diag_kernel<<<512, 64, 0, stream>>>(ws, W, b, out);
}

// Round 16
// 904.408 us; speedup vs baseline: 1.6105x; 1.0303x over previous
//
#include <hip/hip_runtime.h>
#include <stdint.h>

#define Vv 512
#define Ff 1024

typedef unsigned short u16;
typedef unsigned long long u64;
typedef __attribute__((ext_vector_type(8))) short s16x8;
typedef __attribute__((ext_vector_type(4))) float f32x4;

// workspace layout (bytes)
#define OFF_WH  (0ull)
#define OFF_WM  (2ull << 20)
#define OFF_WL  (4ull << 20)
#define OFF_A0  (6ull << 20)
#define OFF_A1  (9ull << 20)
#define OFF_FLG (12ull << 20)

// A buffer: 256 tiles (ig 16 x js 16), tile = 12288 B: [lv 3][o 8][r 32] 16B units;
// element (i=ig*32+r, j=js*64+o*8+e) at tile*12288 + lv*4096 + (o*32+r)*16 + e*2.

// Exact 3-way bf16 truncation split: v == h + m + l (bit-exact, 24 mantissa bits)
__device__ __forceinline__ void split3(float v, u16& h, u16& m, u16& l) {
    unsigned u = __float_as_uint(v);
    float fh = __uint_as_float(u & 0xFFFF0000u);
    h = (u16)(u >> 16);
    float r1 = v - fh;                         // exact
    unsigned u1 = __float_as_uint(r1);
    float fm = __uint_as_float(u1 & 0xFFFF0000u);
    m = (u16)(u1 >> 16);
    float r2 = r1 - fm;                        // exact
    l = (u16)(__float_as_uint(r2) >> 16);
}

__device__ __forceinline__ float bf2f(short v) {
    return __uint_as_float(((unsigned)(u16)v) << 16);
}

// W planes. Wh/Wm frag-major: unit = (((js*4+nq)*16+c)*2+kh)*64 + o*16 + col.
// Wl (per js-block 8192 units, LDS-linear): unit = js*8192 + (c*2+kh)*256 + o*64 + nq*16 + col.
__global__ void wsplit_kernel(const float* __restrict__ W, char* __restrict__ ws) {
    int idx = blockIdx.x * 256 + threadIdx.x;   // 0..131071 (j x k-octet)
    int j = idx >> 7, ko = idx & 127;
    const float* wr = W + (size_t)j * Ff + ko * 8;
    s16x8 vh, vm, vl;
#pragma unroll
    for (int e = 0; e < 8; ++e) {
        u16 h, m, l; split3(wr[e], h, m, l);
        vh[e] = (short)h; vm[e] = (short)m; vl[e] = (short)l;
    }
    int js = j >> 6, nq = (j >> 4) & 3, col = j & 15;
    int c = ko >> 3, kh = (ko >> 2) & 1, o = ko & 3;
    unsigned uhm = (unsigned)((((js * 4 + nq) * 16 + c) * 2 + kh) * 64 + o * 16 + col);
    unsigned ul  = (unsigned)(js * 8192 + (c * 2 + kh) * 256 + o * 64 + nq * 16 + col);
    *(s16x8*)(ws + OFF_WH + (size_t)uhm * 16) = vh;
    *(s16x8*)(ws + OFF_WM + (size_t)uhm * 16) = vm;
    *(s16x8*)(ws + OFF_WL + (size_t)ul * 16)  = vl;
}

// t=0 state into A0 tiles + zero the tile flags (64 B stride)
__global__ void init_kernel(const float* __restrict__ X, const float* __restrict__ b,
                            char* __restrict__ ws) {
    int idx = blockIdx.x * 256 + threadIdx.x;   // 0..65535 (i x j-octet)
    if (idx < 4096) ((unsigned*)(ws + OFF_FLG))[idx] = 0u;
    int i = idx >> 7, jo = idx & 127;
    s16x8 vh, vm, vl;
#pragma unroll
    for (int e = 0; e < 8; ++e) {
        int j = jo * 8 + e;
        float u = b[j];
        if (j < Vv && i != j) u = 0.5f * u + 0.5f * X[j];
        u = fmaxf(u, 0.f);
        u16 h, m, l; split3(u, h, m, l);
        vh[e] = (short)h; vm[e] = (short)m; vl[e] = (short)l;
    }
    int ig = i >> 5, r = i & 31, js = jo >> 3, o = jo & 7;
    size_t tb = (size_t)(ig * 16 + js) * 12288 + (size_t)(o * 32 + r) * 16;
    *(s16x8*)(ws + OFF_A0 + tb)        = vh;
    *(s16x8*)(ws + OFF_A0 + tb + 4096) = vm;
    *(s16x8*)(ws + OFF_A0 + tb + 8192) = vl;
}

#define GST(addr, val) \
    asm volatile("global_store_dwordx2 %0, %1, off sc0 sc1" \
                 :: "v"((void*)(addr)), "v"(val) : "memory")
#define MM(acc_, a_, b_) \
    asm("v_mfma_f32_16x16x32_bf16 %0, %1, %2, %0" : "+v"(acc_) : "v"(a_), "v"(b_))

// Persistent: 256 blocks x 512 thr; block = (ig, js). 8 waves: kh = w&1, nq = w>>1.
// Rotated chunk order (chunk 0 = own tile, staged from epilogue registers).
// EPILOGUE REMAP (vs R12): thread -> (row=(tid>>1)&31, c4=(tid>>6)*8+(tid&1)*4) so
// ownoff == tid*8: slot-0 LDS writes linear (conflict-free) and global coherent
// stores dense 512B/wave/plane. red re-laid as [kh][32][stride 68] (aligned,
// write-conflict-free). Wire format, sync, and fp32 sum order are bit-identical.
__global__ __launch_bounds__(512, 2)
void mega_kernel(const float* __restrict__ X, const float* __restrict__ b,
                 char* __restrict__ ws) {
    extern __shared__ char smem[];   // Wl 131072 | A slots 2x12288 (red 17408 overlays)
    const int tid = threadIdx.x, bid = blockIdx.x;
    const int ig = bid >> 4, js = bid & 15;
    const int lane = tid & 63, l15 = lane & 15, l4 = lane >> 4;
    const int w = tid >> 6, kh = w & 1, nq = w >> 1;

    unsigned* flg = (unsigned*)(ws + OFF_FLG);

    // one-time: Wl 64-col slice -> LDS (linear, async)
    {
        const char* src = ws + OFF_WL + (size_t)js * 131072;
#pragma unroll
        for (int q = 0; q < 16; ++q) {
            unsigned u = (unsigned)(q * 512 + tid) * 16u;
            __builtin_amdgcn_global_load_lds(
                (const __attribute__((address_space(1))) void*)(src + u),
                (__attribute__((address_space(3))) void*)(smem + u), 16, 0, 0);
        }
    }

    // one-time: Wh/Wm -> named register scalars, ROTATED by js (position n = tile (js+n)&15)
    s16x8 Bh0, Bh1, Bh2, Bh3, Bh4, Bh5, Bh6, Bh7, Bh8, Bh9, Bh10, Bh11, Bh12, Bh13, Bh14, Bh15;
    s16x8 Bm0, Bm1, Bm2, Bm3, Bm4, Bm5, Bm6, Bm7, Bm8, Bm9, Bm10, Bm11, Bm12, Bm13, Bm14, Bm15;
    {
        const char* wfrag = ws + OFF_WH +
            (size_t)(((((js * 4 + nq) * 16) * 2 + kh) * 64) + l4 * 16 + l15) * 16;
#define LOADW(n) do {                                                                  \
        const char* wp_ = wfrag + (size_t)(((js + (n)) & 15) * 2048);                  \
        asm volatile("global_load_dwordx4 %0, %1, off"                                 \
                     : "=v"(Bh##n) : "v"((const void*)wp_));                           \
        asm volatile("global_load_dwordx4 %0, %1, off"                                 \
                     : "=v"(Bm##n) : "v"((const void*)(wp_ + (2ull << 20))));          \
    } while (0)
        LOADW(0);  LOADW(1);  LOADW(2);  LOADW(3);
        LOADW(4);  LOADW(5);  LOADW(6);  LOADW(7);
        LOADW(8);  LOADW(9);  LOADW(10); LOADW(11);
        LOADW(12); LOADW(13); LOADW(14); LOADW(15);
#undef LOADW
    }

    // epilogue thread mapping (linear writes): row = (tid>>1)&31, c4 = o*8 + h*4
    const int row = (tid >> 1) & 31;
    const int c4 = ((tid >> 6) << 3) + ((tid & 1) << 2);
    const int i_glob = ig * 32 + row;
    const float4 bbv = *(const float4*)(b + js * 64 + c4);
    float* red = (float*)(smem + 131072);   // [kh][32 rows][stride 68 f32]
    const unsigned ownoff = (unsigned)tid * 8u;   // == ((c4>>3)*32+row)*16 + (c4&7)*2

    // per-thread constant LDS offsets for fragment reads
    const unsigned abase = (unsigned)(((kh * 4 + l4) * 32 + l15) * 16);
    const unsigned a00 = abase,          a01 = abase + 256;             // lv0, mf0/1
    const unsigned a10 = abase + 4096,   a11 = abase + 4096 + 256;      // lv1
    const unsigned a20 = abase + 8192,   a21 = abase + 8192 + 256;      // lv2
    const unsigned bloff = (unsigned)(kh * 4096 + (l4 * 64 + nq * 16 + l15) * 16);

    s16x8 Af00, Af01, Af10, Af11, Af20, Af21, Bl;
    u64 ga0, ga1, ga2, gb0, gb1, gb2, gc0, gc1, gc2;

#define GLDA3(g0_, g1_, g2_, cc) do {                                                  \
        const char* ap_ = tb + (size_t)((cc) * 12288) + (size_t)tid * 8;               \
        asm volatile("global_load_dwordx2 %0, %1, off sc0 sc1"                         \
                     : "=v"(g0_) : "v"((const void*)ap_) : "memory");                  \
        asm volatile("global_load_dwordx2 %0, %1, off sc0 sc1"                         \
                     : "=v"(g1_) : "v"((const void*)(ap_ + 4096)) : "memory");         \
        asm volatile("global_load_dwordx2 %0, %1, off sc0 sc1"                         \
                     : "=v"(g2_) : "v"((const void*)(ap_ + 8192)) : "memory");         \
    } while (0)
#define DSWR3(slot, g0_, g1_, g2_) do {                                                \
        char* wp_ = smem + 131072 + (slot) * 12288 + (size_t)tid * 8;                  \
        *(u64*)(wp_) = g0_; *(u64*)(wp_ + 4096) = g1_; *(u64*)(wp_ + 8192) = g2_;      \
    } while (0)
#define DSRD7(slot, cc) do {                                                           \
        const char* sb_ = smem + 131072 + (slot) * 12288;                              \
        Af00 = *(const s16x8*)(sb_ + a00); Af01 = *(const s16x8*)(sb_ + a01);          \
        Af10 = *(const s16x8*)(sb_ + a10); Af11 = *(const s16x8*)(sb_ + a11);          \
        Af20 = *(const s16x8*)(sb_ + a20); Af21 = *(const s16x8*)(sb_ + a21);          \
        Bl = *(const s16x8*)(smem + (size_t)((cc) * 8192) + bloff);                    \
    } while (0)
#define MFMA12(n) do {                                                                 \
        __builtin_amdgcn_s_setprio(1);                                                 \
        MM(acc0, Af00, Bh##n); MM(acc1, Af01, Bh##n);                                  \
        MM(acc0, Af00, Bm##n); MM(acc1, Af01, Bm##n);                                  \
        MM(acc0, Af10, Bh##n); MM(acc1, Af11, Bh##n);                                  \
        MM(acc0, Af00, Bl);    MM(acc1, Af01, Bl);                                     \
        MM(acc0, Af20, Bh##n); MM(acc1, Af21, Bh##n);                                  \
        MM(acc0, Af10, Bm##n); MM(acc1, Af11, Bm##n);                                  \
        __builtin_amdgcn_s_setprio(0);                                                 \
    } while (0)
// chunk n in [0..12]: issue tile (n+3) into set n%3, compute n, hand off n+1 from set (n+1)%3
#define CHUNK(n, P0, P1, P2, Q0, Q1, Q2, VM) do {                                      \
        __builtin_amdgcn_sched_barrier(0);                                             \
        MFMA12(n);                                                                     \
        __builtin_amdgcn_sched_barrier(0);                                             \
        asm volatile("s_waitcnt vmcnt(" #VM ")" ::: "memory");                         \
        DSWR3(((n) + 1) & 1, Q0, Q1, Q2);                                              \
        asm volatile("s_waitcnt lgkmcnt(0)" ::: "memory");                             \
        __builtin_amdgcn_s_barrier();                                                  \
        DSRD7(((n) + 1) & 1, (js + (n) + 1) & 15);                                     \
    } while (0)

    // prologue: own tile of step-1 input (A0, written by init_kernel) -> slot 0
    {
        const char* own0 = ws + OFF_A0 + (size_t)(ig * 16 + js) * 12288;
        const char* tb = own0;   // GLDA3 uses tb + cc*12288 with cc=0
        GLDA3(ga0, ga1, ga2, 0);
        asm volatile("s_waitcnt vmcnt(0)" ::: "memory");
        DSWR3(0, ga0, ga1, ga2);
    }
    __syncthreads();   // Wl + W regs + slot0 ready (drains vmcnt/lgkmcnt)

    for (int t = 1; t <= 126; ++t) {
        char* srcA = ws + ((t & 1) ? OFF_A0 : OFF_A1);
        char* dstA = ws + ((t & 1) ? OFF_A1 : OFF_A0);
        const char* tb = srcA + (size_t)ig * 16 * 12288;

        // chunk 0 fragments come from our own slot-0 staging — no flag, no load
        DSRD7(0, js);

        // per-wave poll for the 15 foreign producer tiles (lanes 0..15, no block sync)
        if (lane < 16) {
            while ((int)__hip_atomic_load(&flg[(ig * 16 + lane) * 16], __ATOMIC_RELAXED,
                                          __HIP_MEMORY_SCOPE_AGENT) < t - 1)
                __builtin_amdgcn_s_sleep(1);
        }
        asm volatile("" ::: "memory");

        // 3-deep prefetch: tiles at positions 1,2 (position 3 issued inside chunk 0)
        GLDA3(gb0, gb1, gb2, (js + 1) & 15);
        GLDA3(gc0, gc1, gc2, (js + 2) & 15);

        f32x4 acc0 = (f32x4){0.f, 0.f, 0.f, 0.f};
        f32x4 acc1 = (f32x4){0.f, 0.f, 0.f, 0.f};

        GLDA3(ga0, ga1, ga2, (js + 3) & 15);
        CHUNK(0,  ga0, ga1, ga2, gb0, gb1, gb2, 6);
        GLDA3(gb0, gb1, gb2, (js + 4) & 15);
        CHUNK(1,  gb0, gb1, gb2, gc0, gc1, gc2, 6);
        GLDA3(gc0, gc1, gc2, (js + 5) & 15);
        CHUNK(2,  gc0, gc1, gc2, ga0, ga1, ga2, 6);
        GLDA3(ga0, ga1, ga2, (js + 6) & 15);
        CHUNK(3,  ga0, ga1, ga2, gb0, gb1, gb2, 6);
        GLDA3(gb0, gb1, gb2, (js + 7) & 15);
        CHUNK(4,  gb0, gb1, gb2, gc0, gc1, gc2, 6);
        GLDA3(gc0, gc1, gc2, (js + 8) & 15);
        CHUNK(5,  gc0, gc1, gc2, ga0, ga1, ga2, 6);
        GLDA3(ga0, ga1, ga2, (js + 9) & 15);
        CHUNK(6,  ga0, ga1, ga2, gb0, gb1, gb2, 6);
        GLDA3(gb0, gb1, gb2, (js + 10) & 15);
        CHUNK(7,  gb0, gb1, gb2, gc0, gc1, gc2, 6);
        GLDA3(gc0, gc1, gc2, (js + 11) & 15);
        CHUNK(8,  gc0, gc1, gc2, ga0, ga1, ga2, 6);
        GLDA3(ga0, ga1, ga2, (js + 12) & 15);
        CHUNK(9,  ga0, ga1, ga2, gb0, gb1, gb2, 6);
        GLDA3(gb0, gb1, gb2, (js + 13) & 15);
        CHUNK(10, gb0, gb1, gb2, gc0, gc1, gc2, 6);
        GLDA3(gc0, gc1, gc2, (js + 14) & 15);
        CHUNK(11, gc0, gc1, gc2, ga0, ga1, ga2, 6);
        GLDA3(ga0, ga1, ga2, (js + 15) & 15);
        CHUNK(12, ga0, ga1, ga2, gb0, gb1, gb2, 6);
        CHUNK(13, ga0, ga1, ga2, gc0, gc1, gc2, 3);   // no issue; wait set14
        CHUNK(14, ga0, ga1, ga2, ga0, ga1, ga2, 0);   // no issue; wait set15
        MFMA12(15);

        __builtin_amdgcn_s_barrier();         // all waves done with A slots (red overlay)
        asm volatile("s_nop 7\n\ts_nop 7");   // MFMA->VALU read hazard guard

        // kh-pair reduction through LDS: red[kh][rr][stride 68]
#pragma unroll
        for (int r = 0; r < 4; ++r)
            red[kh * 2176 + (l4 * 4 + r) * 68 + nq * 16 + l15] = acc0[r];
#pragma unroll
        for (int r = 0; r < 4; ++r)
            red[kh * 2176 + (16 + l4 * 4 + r) * 68 + nq * 16 + l15] = acc1[r];
        __syncthreads();

        // read partials, then a barrier before the own-tile LDS overwrite (WAR)
        float4 p0 = *(const float4*)&red[row * 68 + c4];
        float4 p1 = *(const float4*)&red[2176 + row * 68 + c4];
        __syncthreads();

        // epilogue: bias + mask + relu + exact re-split; store to global AND slot 0
        {
            float s0 = p0.x + p1.x, s1 = p0.y + p1.y, s2 = p0.z + p1.z, s3 = p0.w + p1.w;
            const float* xt = X + (size_t)t * Vv;
            float u0 = s0 + bbv.x, u1 = s1 + bbv.y, u2 = s2 + bbv.z, u3 = s3 + bbv.w;
            if (js < 8) {
                int j0 = js * 64 + c4;
                float x0 = xt[j0], x1 = xt[j0 + 1], x2 = xt[j0 + 2], x3 = xt[j0 + 3];
                if (i_glob != j0)     u0 = 0.5f * u0 + 0.5f * x0;
                if (i_glob != j0 + 1) u1 = 0.5f * u1 + 0.5f * x1;
                if (i_glob != j0 + 2) u2 = 0.5f * u2 + 0.5f * x2;
                if (i_glob != j0 + 3) u3 = 0.5f * u3 + 0.5f * x3;
            }
            u0 = fmaxf(u0, 0.f); u1 = fmaxf(u1, 0.f);
            u2 = fmaxf(u2, 0.f); u3 = fmaxf(u3, 0.f);
            u16 h0, m0, l0, h1, m1, l1, h2, m2, l2, h3, m3, l3;
            split3(u0, h0, m0, l0); split3(u1, h1, m1, l1);
            split3(u2, h2, m2, l2); split3(u3, h3, m3, l3);
            u64 ph = (u64)h0 | ((u64)h1 << 16) | ((u64)h2 << 32) | ((u64)h3 << 48);
            u64 pm = (u64)m0 | ((u64)m1 << 16) | ((u64)m2 << 32) | ((u64)m3 << 48);
            u64 pl = (u64)l0 | ((u64)l1 << 16) | ((u64)l2 << 32) | ((u64)l3 << 48);
            size_t tbo = (size_t)(ig * 16 + js) * 12288 + ownoff;
            GST(dstA + tbo, ph);
            GST(dstA + tbo + 4096, pm);
            GST(dstA + tbo + 8192, pl);
            // own tile -> slot 0 for next step (linear tid*8 — conflict-free)
            *(u64*)(smem + 131072 + ownoff) = ph;
            *(u64*)(smem + 131072 + ownoff + 4096) = pm;
            *(u64*)(smem + 131072 + ownoff + 8192) = pl;
        }
        asm volatile("s_waitcnt vmcnt(0)" ::: "memory");
        __syncthreads();   // stores drained + slot0 staged
        if (tid == 0)
            __hip_atomic_store(&flg[(ig * 16 + js) * 16], (unsigned)t, __ATOMIC_RELAXED,
                               __HIP_MEMORY_SCOPE_AGENT);
    }
#undef GLDA3
#undef DSWR3
#undef DSRD7
#undef MFMA12
#undef CHUNK
}

// Final: out[i] = dot(R126[i,:], W[i,:]) + b[i]; R126 in A0 tiles (h+m+l exact)
__global__ void diag_kernel(const char* __restrict__ ws, const float* __restrict__ W,
                            const float* __restrict__ b, float* __restrict__ out) {
    int i = blockIdx.x, lane = threadIdx.x;
    const char* A0 = ws + OFF_A0;
    float s = 0.f;
#pragma unroll
    for (int rep = 0; rep < 2; ++rep) {
        int ko = lane + rep * 64;                 // k-octet 0..127
        int js = ko >> 3, o = ko & 7;
        size_t tb = (size_t)((i >> 5) * 16 + js) * 12288
                  + (size_t)(o * 32 + (i & 31)) * 16;
        s16x8 vh = *(const s16x8*)(A0 + tb);
        s16x8 vm = *(const s16x8*)(A0 + tb + 4096);
        s16x8 vl = *(const s16x8*)(A0 + tb + 8192);
        const float* wr = W + (size_t)i * Ff + ko * 8;
#pragma unroll
        for (int e = 0; e < 8; ++e)
            s += (bf2f(vh[e]) + bf2f(vm[e]) + bf2f(vl[e])) * wr[e];
    }
#pragma unroll
    for (int off = 32; off > 0; off >>= 1) s += __shfl_down(s, off);
    if (lane == 0) out[i] = s + b[i];
}

extern "C" void kernel_launch(void* const* d_in, const int* in_sizes, int n_in,
                              void* d_out, int out_size, void* d_ws, size_t ws_size,
                              hipStream_t stream) {
    const float* X = (const float*)d_in[0];   // (128, 512)
    const float* W = (const float*)d_in[1];   // (1024, 1024)
    const float* b = (const float*)d_in[2];   // (1024,)
    float* out = (float*)d_out;
    char* ws = (char*)d_ws;

    hipFuncSetAttribute(reinterpret_cast<const void*>(mega_kernel),
                        hipFuncAttributeMaxDynamicSharedMemorySize, 155648);

    wsplit_kernel<<<512, 256, 0, stream>>>(W, ws);
    init_kernel<<<256, 256, 0, stream>>>(X, b, ws);
    mega_kernel<<<256, 512, 155648, stream>>>(X, b, ws);
    diag_kernel<<<512, 64, 0, stream>>>(ws, W, b, out);
}